// Round 7
// baseline (399.541 us; speedup 1.0000x reference)
//
#include <hip/hip_runtime.h>
#include <math.h>

// Problem constants (from setup_inputs)
constexpr int B   = 4;
constexpr int N   = 8192;
constexpr int M   = 2048;
constexpr int C1  = 128;
constexpr int C2  = 256;
constexpr int HCH = 256;   // H
constexpr int CIN = 384;   // C2 + C1
constexpr float BN_EPS = 1e-5f;
constexpr float SLOPE  = 0.2f;
constexpr float BN_CNT = (float)(B * N);   // BN reduces over (B, N)

typedef __attribute__((ext_vector_type(8))) short short8;   // 8 bf16 (4 VGPR)
typedef __attribute__((ext_vector_type(4))) float f32x4;    // MFMA C/D

// f32 -> bf16 round-to-nearest-even (bit twiddle; no hip_bf16 API dependence)
__device__ __forceinline__ unsigned short bfh(float x) {
  unsigned int u = __float_as_uint(x);
  return (unsigned short)((u + 0x7fffu + ((u >> 16) & 1u)) >> 16);
}
__device__ __forceinline__ float bf2f(unsigned short h) {
  return __uint_as_float((unsigned int)h << 16);
}
__device__ __forceinline__ unsigned int pk(unsigned short a, unsigned short b) {
  return (unsigned int)a | ((unsigned int)b << 16);
}

// ---------------- zero stats ----------------
__global__ void k_zero(float* __restrict__ stats) {
  int i = blockIdx.x * blockDim.x + threadIdx.x;
  if (i < 1024) stats[i] = 0.f;
}

// ---------------- three_nn + inverse-distance weights ----------------
__global__ __launch_bounds__(256) void k_nn(const float* __restrict__ xyz1,
                                            const float* __restrict__ xyz2,
                                            float* __restrict__ wgt,
                                            int* __restrict__ idxo) {
  __shared__ float4 q[4][512];          // 32 KB: [slice][ref]
  __shared__ float  md[4][64][3];
  __shared__ int    mi[4][64][3];
  const int tid = threadIdx.x;
  const int b   = blockIdx.y;
  const int n0  = blockIdx.x * 64;

  const float* src = xyz2 + (size_t)b * M * 3;
  for (int i = tid; i < M; i += 256) {
    float x = src[i*3+0], y = src[i*3+1], z = src[i*3+2];
    q[i >> 9][i & 511] = make_float4(x, y, z, x*x + y*y + z*z);
  }
  __syncthreads();

  const int w = tid >> 6;
  const int t = tid & 63;
  const int n = n0 + t;
  const float* p = xyz1 + ((size_t)b * N + n) * 3;
  const float px = p[0], py = p[1], pz = p[2];
  const float n1 = px*px + py*py + pz*pz;

  float d0 = 3.4e38f, d1 = 3.4e38f, d2 = 3.4e38f;
  int   j0 = 0, j1 = 0, j2 = 0;
  const float4* qs = q[w];
  #pragma unroll 4
  for (int r = 0; r < 512; ++r) {
    float4 c = qs[r];
    float dot = px*c.x + py*c.y + pz*c.z;
    float d = fmaf(-2.f, dot, n1 + c.w);
    if (d < d2) {
      int m = (w << 9) + r;
      if (d < d1) {
        if (d < d0) { d2 = d1; j2 = j1; d1 = d0; j1 = j0; d0 = d; j0 = m; }
        else        { d2 = d1; j2 = j1; d1 = d;  j1 = m; }
      } else        { d2 = d;  j2 = m; }
    }
  }
  md[w][t][0] = d0; md[w][t][1] = d1; md[w][t][2] = d2;
  mi[w][t][0] = j0; mi[w][t][1] = j1; mi[w][t][2] = j2;
  __syncthreads();

  if (tid < 64) {
    float e0 = 3.4e38f, e1 = 3.4e38f, e2 = 3.4e38f;
    int   i0 = 0, i1 = 0, i2 = 0;
    #pragma unroll
    for (int s = 0; s < 4; ++s) {
      #pragma unroll
      for (int k = 0; k < 3; ++k) {
        float d = md[s][tid][k];
        int   m = mi[s][tid][k];
        if (d < e2) {
          if (d < e1) {
            if (d < e0) { e2 = e1; i2 = i1; e1 = e0; i1 = i0; e0 = d; i0 = m; }
            else        { e2 = e1; i2 = i1; e1 = d;  i1 = m; }
          } else        { e2 = d;  i2 = m; }
        }
      }
    }
    e0 = fmaxf(e0, 1e-10f); e1 = fmaxf(e1, 1e-10f); e2 = fmaxf(e2, 1e-10f);
    float r0 = 1.f / e0, r1 = 1.f / e1, r2 = 1.f / e2;
    float s  = r0 + r1 + r2;
    size_t base = ((size_t)b * N + n0 + tid) * 3;
    wgt[base+0] = r0 / s;  wgt[base+1] = r1 / s;  wgt[base+2] = r2 / s;
    idxo[base+0] = i0;     idxo[base+1] = i1;     idxo[base+2] = i2;
  }
}

// ---------------- transpose points2: (B,C2,M) -> (B,M,C2) ----------------
__global__ __launch_bounds__(256) void k_tr(const float* __restrict__ P2,
                                            float* __restrict__ P2T) {
  __shared__ float t[32][33];
  const int b  = blockIdx.z;
  const int m0 = blockIdx.x * 32;
  const int c0 = blockIdx.y * 32;
  const int tx = threadIdx.x & 31;
  const int ty = threadIdx.x >> 5;
  const float* src = P2 + (size_t)b * C2 * M;
  #pragma unroll
  for (int j = 0; j < 4; ++j)
    t[ty + j*8][tx] = src[(size_t)(c0 + ty + j*8) * M + m0 + tx];
  __syncthreads();
  float* dst = P2T + (size_t)b * M * C2;
  #pragma unroll
  for (int j = 0; j < 4; ++j)
    dst[(size_t)(m0 + ty + j*8) * C2 + c0 + tx] = t[tx][ty + j*8];
}

// ---------------- interpolate (from P2T) + concat points1 -> X (B,CIN,N) ----------------
__global__ __launch_bounds__(256) void k_interp(const float* __restrict__ P2T,
                                                const float* __restrict__ points1,
                                                const float* __restrict__ wgt,
                                                const int* __restrict__ idx,
                                                float* __restrict__ X) {
  const int b = blockIdx.y;
  const int n = blockIdx.x * 256 + threadIdx.x;
  const size_t base = (size_t)b * N + n;
  const int i0 = idx[base*3+0], i1 = idx[base*3+1], i2 = idx[base*3+2];
  const float w0 = wgt[base*3+0], w1 = wgt[base*3+1], w2 = wgt[base*3+2];
  const float4* r0 = (const float4*)(P2T + ((size_t)b * M + i0) * C2);
  const float4* r1 = (const float4*)(P2T + ((size_t)b * M + i1) * C2);
  const float4* r2 = (const float4*)(P2T + ((size_t)b * M + i2) * C2);
  float* Xb = X + (size_t)b * CIN * N + n;
  #pragma unroll 4
  for (int c4 = 0; c4 < C2/4; ++c4) {
    float4 a0 = r0[c4], a1 = r1[c4], a2 = r2[c4];
    Xb[(size_t)(c4*4+0) * N] = w0*a0.x + w1*a1.x + w2*a2.x;
    Xb[(size_t)(c4*4+1) * N] = w0*a0.y + w1*a1.y + w2*a2.y;
    Xb[(size_t)(c4*4+2) * N] = w0*a0.z + w1*a1.z + w2*a2.z;
    Xb[(size_t)(c4*4+3) * N] = w0*a0.w + w1*a1.w + w2*a2.w;
  }
  const float* p1 = points1 + (size_t)b * C1 * N + n;
  float* Xc = Xb + (size_t)C2 * N;
  #pragma unroll 4
  for (int c = 0; c < C1; ++c) Xc[(size_t)c * N] = p1[(size_t)c * N];
}

// ---------------- bf16x3 MFMA GEMM: Y(B,HCH,N) = W(HCH,K) @ Xin(B,K,N) + bias ----------------
// f32 operands split into hi/lo bf16 (Dekker-exact); W.X ~= Wh.Xh + Wh.Xl + Wl.Xh.
// Tile 128x128, BK=32, 4 waves (2x2), each wave 64x64 via 4x4 16x16x32 fragments.
// LDS rows padded to 40 bf16 (80 B) -> worst 2-way bank alias on ds_read_b128 (free).
// XFORM: BN1 affine + LeakyReLU applied to Xin during staging (coef[c]=a, coef[256+c]=b).
// Epilogue: bias add, Y store, per-channel sum/sumsq atomics into stats.
template <int K, bool XFORM>
__global__ __launch_bounds__(256, 2) void k_gemm(const float* __restrict__ Wm,
                                                 const float* __restrict__ bias,
                                                 const float* __restrict__ Xin,
                                                 const float* __restrict__ coef,
                                                 float* __restrict__ Yout,
                                                 float* __restrict__ stats) {
  constexpr int BM = 128, BN = 128, BK = 32, RL = 40;   // RL: padded row (bf16)
  __shared__ unsigned short Wh[BM*RL], Wl[BM*RL], Xh[BN*RL], Xl[BN*RL];  // 40 KB

  const int tid = threadIdx.x;
  const int n0 = blockIdx.x * BN;
  const int o0 = blockIdx.y * BM;
  const int b  = blockIdx.z;
  const float* Xb = Xin + (size_t)b * K * N;

  const int sr = tid >> 1;          // staging row 0..127 (o for W, n for X)
  const int kh = (tid & 1) * 16;    // k-half 0 / 16

  const int lane = tid & 63;
  const int wv = tid >> 6;          // wave 0..3
  const int wm = wv >> 1, wn = wv & 1;
  const int lr = lane & 15;         // frag row (A) / col (B) / col (C)
  const int lk = (lane >> 4) * 8;   // frag k-offset

  f32x4 acc[4][4] = {};

  for (int k0 = 0; k0 < K; k0 += BK) {
    { // ---- stage W tile: rows o0..o0+127, k k0..k0+31 (k-contiguous reads) ----
      const float* wp = Wm + (size_t)(o0 + sr) * K + k0 + kh;
      float xv[16];
      *(float4*)&xv[0]  = *(const float4*)(wp + 0);
      *(float4*)&xv[4]  = *(const float4*)(wp + 4);
      *(float4*)&xv[8]  = *(const float4*)(wp + 8);
      *(float4*)&xv[12] = *(const float4*)(wp + 12);
      unsigned short h[16], l[16];
      #pragma unroll
      for (int i = 0; i < 16; ++i) {
        h[i] = bfh(xv[i]);
        l[i] = bfh(xv[i] - bf2f(h[i]));
      }
      uint4* dh = (uint4*)&Wh[sr*RL + kh];
      uint4* dl = (uint4*)&Wl[sr*RL + kh];
      dh[0] = make_uint4(pk(h[0],h[1]),  pk(h[2],h[3]),  pk(h[4],h[5]),  pk(h[6],h[7]));
      dh[1] = make_uint4(pk(h[8],h[9]),  pk(h[10],h[11]),pk(h[12],h[13]),pk(h[14],h[15]));
      dl[0] = make_uint4(pk(l[0],l[1]),  pk(l[2],l[3]),  pk(l[4],l[5]),  pk(l[6],l[7]));
      dl[1] = make_uint4(pk(l[8],l[9]),  pk(l[10],l[11]),pk(l[12],l[13]),pk(l[14],l[15]));
    }
    { // ---- stage X tile transposed: [n][k], strided-coalesced global reads ----
      float xv[16];
      #pragma unroll
      for (int i = 0; i < 16; ++i)
        xv[i] = Xb[(size_t)(k0 + kh + i) * N + n0 + sr];
      if constexpr (XFORM) {
        #pragma unroll
        for (int i = 0; i < 16; ++i) {
          const int c = k0 + kh + i;
          float t = fmaf(coef[c], xv[i], coef[256 + c]);
          xv[i] = t >= 0.f ? t : SLOPE * t;
        }
      }
      unsigned short h[16], l[16];
      #pragma unroll
      for (int i = 0; i < 16; ++i) {
        h[i] = bfh(xv[i]);
        l[i] = bfh(xv[i] - bf2f(h[i]));
      }
      uint4* dh = (uint4*)&Xh[sr*RL + kh];
      uint4* dl = (uint4*)&Xl[sr*RL + kh];
      dh[0] = make_uint4(pk(h[0],h[1]),  pk(h[2],h[3]),  pk(h[4],h[5]),  pk(h[6],h[7]));
      dh[1] = make_uint4(pk(h[8],h[9]),  pk(h[10],h[11]),pk(h[12],h[13]),pk(h[14],h[15]));
      dl[0] = make_uint4(pk(l[0],l[1]),  pk(l[2],l[3]),  pk(l[4],l[5]),  pk(l[6],l[7]));
      dl[1] = make_uint4(pk(l[8],l[9]),  pk(l[10],l[11]),pk(l[12],l[13]),pk(l[14],l[15]));
    }
    __syncthreads();

    short8 bh[4], bl[4];
    #pragma unroll
    for (int n = 0; n < 4; ++n) {
      bh[n] = *(const short8*)&Xh[(wn*64 + n*16 + lr)*RL + lk];
      bl[n] = *(const short8*)&Xl[(wn*64 + n*16 + lr)*RL + lk];
    }
    #pragma unroll
    for (int m = 0; m < 4; ++m) {
      short8 ah = *(const short8*)&Wh[(wm*64 + m*16 + lr)*RL + lk];
      short8 al = *(const short8*)&Wl[(wm*64 + m*16 + lr)*RL + lk];
      #pragma unroll
      for (int n = 0; n < 4; ++n) {
        acc[m][n] = __builtin_amdgcn_mfma_f32_16x16x32_bf16(ah, bh[n], acc[m][n], 0, 0, 0);
        acc[m][n] = __builtin_amdgcn_mfma_f32_16x16x32_bf16(ah, bl[n], acc[m][n], 0, 0, 0);
        acc[m][n] = __builtin_amdgcn_mfma_f32_16x16x32_bf16(al, bh[n], acc[m][n], 0, 0, 0);
      }
    }
    __syncthreads();
  }

  // ---- epilogue: bias, store Y (f32), per-channel stats ----
  // C layout (m89): row = (lane>>4)*4 + r, col = lane&15
  #pragma unroll
  for (int m = 0; m < 4; ++m) {
    #pragma unroll
    for (int r = 0; r < 4; ++r) {
      const int o = o0 + wm*64 + m*16 + (lane >> 4)*4 + r;
      const float bi = bias[o];
      float s = 0.f, q = 0.f;
      #pragma unroll
      for (int n = 0; n < 4; ++n) {
        float v = acc[m][n][r] + bi;
        Yout[((size_t)b * HCH + o) * N + n0 + wn*64 + n*16 + lr] = v;
        s += v; q += v*v;
      }
      #pragma unroll
      for (int off = 1; off < 16; off <<= 1) {
        s += __shfl_xor(s, off);
        q += __shfl_xor(q, off);
      }
      if (lr == 0) {
        atomicAdd(&stats[o], s);
        atomicAdd(&stats[256 + o], q);
      }
    }
  }
}

// ---------------- BN finalize: stats -> per-channel (a, b) ----------------
__global__ void k_fin(const float* __restrict__ stats,
                      const float* __restrict__ gamma,
                      const float* __restrict__ beta,
                      float* __restrict__ coef) {
  const int c = threadIdx.x;
  const float mean = stats[c] / BN_CNT;
  const float var  = stats[256 + c] / BN_CNT - mean * mean;
  const float a    = gamma[c] / sqrtf(var + BN_EPS);
  coef[c]       = a;
  coef[256 + c] = fmaf(-a, mean, beta[c]);
}

// ---------------- final BN apply + LeakyReLU -> out ----------------
__global__ __launch_bounds__(256) void k_apply(const float* __restrict__ Y,
                                               const float* __restrict__ coef,
                                               float* __restrict__ out) {
  const size_t total = (size_t)B * HCH * N / 4;
  const float4* y4 = (const float4*)Y;
  float4* o4 = (float4*)out;
  for (size_t f = (size_t)blockIdx.x * blockDim.x + threadIdx.x; f < total;
       f += (size_t)gridDim.x * blockDim.x) {
    const int c = (int)((f / (N / 4)) % HCH);
    const float a = coef[c], bb = coef[256 + c];
    float4 v = y4[f];
    float t;
    t = fmaf(a, v.x, bb); v.x = t >= 0.f ? t : SLOPE * t;
    t = fmaf(a, v.y, bb); v.y = t >= 0.f ? t : SLOPE * t;
    t = fmaf(a, v.z, bb); v.z = t >= 0.f ? t : SLOPE * t;
    t = fmaf(a, v.w, bb); v.w = t >= 0.f ? t : SLOPE * t;
    o4[f] = v;
  }
}

extern "C" void kernel_launch(void* const* d_in, const int* in_sizes, int n_in,
                              void* d_out, int out_size, void* d_ws, size_t ws_size,
                              hipStream_t stream) {
  const float* xyz1    = (const float*)d_in[0];
  const float* xyz2    = (const float*)d_in[1];
  const float* points1 = (const float*)d_in[2];
  const float* points2 = (const float*)d_in[3];
  const float* W1      = (const float*)d_in[4];
  const float* b1      = (const float*)d_in[5];
  const float* gamma1  = (const float*)d_in[6];
  const float* beta1   = (const float*)d_in[7];
  const float* W2      = (const float*)d_in[8];
  const float* b2      = (const float*)d_in[9];
  const float* gamma2  = (const float*)d_in[10];
  const float* beta2   = (const float*)d_in[11];

  float* ws = (float*)d_ws;
  float* wgt    = ws;                                // B*N*3        = 98304
  int*   idx    = (int*)(ws + (size_t)B * N * 3);    // B*N*3        = 98304
  float* P2T    = ws + 2 * (size_t)B * N * 3;        // B*M*C2       = 2097152
  float* Xbuf   = P2T + (size_t)B * M * C2;          // B*CIN*N      = 12582912
  float* Y1     = Xbuf + (size_t)B * CIN * N;        // B*HCH*N      = 8388608
  float* Y2     = Xbuf;                              // alias: X dead after GEMM1
  float* stats1 = Y1 + (size_t)B * HCH * N;          // 512
  float* stats2 = stats1 + 512;                      // 512
  float* coef1  = stats2 + 512;                      // 512
  float* coef2  = coef1 + 512;                       // 512

  k_zero<<<4, 256, 0, stream>>>(stats1);  // zeroes stats1+stats2 (1024 floats)
  k_nn<<<dim3(N / 64, B), 256, 0, stream>>>(xyz1, xyz2, wgt, idx);
  k_tr<<<dim3(M / 32, C2 / 32, B), 256, 0, stream>>>(points2, P2T);
  k_interp<<<dim3(N / 256, B), 256, 0, stream>>>(P2T, points1, wgt, idx, Xbuf);
  k_gemm<CIN, false><<<dim3(N / 128, HCH / 128, B), 256, 0, stream>>>(W1, b1, Xbuf, nullptr, Y1, stats1);
  k_fin<<<1, 256, 0, stream>>>(stats1, gamma1, beta1, coef1);
  k_gemm<HCH, true><<<dim3(N / 128, HCH / 128, B), 256, 0, stream>>>(W2, b2, Y1, coef1, Y2, stats2);
  k_fin<<<1, 256, 0, stream>>>(stats2, gamma2, beta2, coef2);
  k_apply<<<2048, 256, 0, stream>>>(Y2, coef2, (float*)d_out);
}